// Round 3
// baseline (198.745 us; speedup 1.0000x reference)
//
#include <hip/hip_runtime.h>

// Problem constants (from setup_inputs): B=32, H=W=1024, N=96 boxes/batch.
#define BATCH 32
#define HDIM 1024
#define WDIM 1024
#define NBOX 96
#define THREADS 256
#define WAVES_PER_BLOCK (THREADS / 64)
#define ROWS_PER_WAVE 4
// LDS row layout: col c stored at word c + (c>>4)  (stride-17 per 16-elem chunk).
// Written words are 17L+j, j in [0,16) -> lookups c+(c>>4) never hit the
// gap slots 17L+16. Slot 1087 (=17*63+16) is a gap -> zero sentinel.
#define LDS_STRIDE 1088
#define ZERO_SLOT 1087

__device__ __forceinline__ int padidx(int c) { return c + (c >> 4); }

// ---------------------------------------------------------------------------
// Kernel 0: zero the per-box accumulators (ws is poisoned 0xAA by harness).
// ---------------------------------------------------------------------------
__global__ void zero_ws_kernel(float* __restrict__ ws) {
    int i = blockIdx.x * blockDim.x + threadIdx.x;
    if (i < BATCH * NBOX) ws[i] = 0.0f;
}

// ---------------------------------------------------------------------------
// Kernel 1: wave-independent row prefix + box accumulation. NO __syncthreads.
// Each wave owns ROWS_PER_WAVE rows of one batch image and a private LDS
// region. Lane holds 16 contiguous columns [16*lane, 16*lane+16).
// box_sum(b,n) = sum over rows i in [y1,y2) of (P_i[x2] - P_i[x1]),
// with i the BATCH-LOCAL row index (bug in R2: used global row index).
// ---------------------------------------------------------------------------
__global__ __launch_bounds__(THREADS) void box_accum_kernel(
    const float* __restrict__ img,
    const int* __restrict__ bboxes,
    float* __restrict__ ws_box) {

    __shared__ float lds[WAVES_PER_BLOCK * LDS_STRIDE];   // 17408 B

    const int t = threadIdx.x;
    const int lane = t & 63;
    const int wave = t >> 6;
    float* __restrict__ P = lds + wave * LDS_STRIDE;

    const int gwave = blockIdx.x * WAVES_PER_BLOCK + wave;
    const int row0 = gwave * ROWS_PER_WAVE;          // global row; 4 | 1024 -> no batch crossing
    const int b = row0 / HDIM;
    const int hrow0 = row0 - b * HDIM;               // batch-local row for y-compare

    if (lane == 0) P[ZERO_SLOT] = 0.0f;              // sentinel for x1==0 reads

    // --- box params: lane owns box `lane`, and box `lane+64` if lane<32 ---
    const int4* __restrict__ bb = (const int4*)bboxes + b * NBOX;
    int y1a = 0, y2a = 0, ra = 0, la = ZERO_SLOT;
    int y1b = 0, y2b = 0, rb = 0, lb = ZERO_SLOT;
    bool va = false, vb = false;
    {
        int4 q = bb[lane];                           // lane < 96 always (NBOX=96>64)
        int x1 = min(max(q.x, 0), WDIM), x2 = min(max(q.z, 0), WDIM);
        y1a = min(max(q.y, 0), WDIM);  y2a = min(max(q.w, 0), WDIM);
        va = (x2 > x1);
        if (va) { ra = padidx(x2 - 1); la = (x1 > 0) ? padidx(x1 - 1) : ZERO_SLOT; }
    }
    if (lane < NBOX - 64) {
        int4 q = bb[64 + lane];
        int x1 = min(max(q.x, 0), WDIM), x2 = min(max(q.z, 0), WDIM);
        y1b = min(max(q.y, 0), WDIM);  y2b = min(max(q.w, 0), WDIM);
        vb = (x2 > x1);
        if (vb) { rb = padidx(x2 - 1); lb = (x1 > 0) ? padidx(x1 - 1) : ZERO_SLOT; }
    }

    float acca = 0.0f, accb = 0.0f;
    const float* rowptr = img + (size_t)row0 * WDIM + lane * 16;

    for (int r = 0; r < ROWS_PER_WAVE; ++r) {
        // 4x float4 = lane's one 64B cache line, all 4 issue back-to-back
        const float4* lp = (const float4*)(rowptr + (size_t)r * WDIM);
        float4 v0 = lp[0], v1 = lp[1], v2 = lp[2], v3 = lp[3];

        float p[16];
        p[0]  = v0.x;        p[1]  = p[0]  + v0.y;
        p[2]  = p[1] + v0.z; p[3]  = p[2]  + v0.w;
        p[4]  = p[3] + v1.x; p[5]  = p[4]  + v1.y;
        p[6]  = p[5] + v1.z; p[7]  = p[6]  + v1.w;
        p[8]  = p[7] + v2.x; p[9]  = p[8]  + v2.y;
        p[10] = p[9] + v2.z; p[11] = p[10] + v2.w;
        p[12] = p[11]+ v3.x; p[13] = p[12] + v3.y;
        p[14] = p[13]+ v3.z; p[15] = p[14] + v3.w;

        // one wave-inclusive scan of lane totals
        float T = p[15];
        float wscan = T;
        #pragma unroll
        for (int off = 1; off < 64; off <<= 1) {
            float u = __shfl_up(wscan, off, 64);
            if (lane >= off) wscan += u;
        }
        float E = wscan - T;   // exclusive base for this lane's chunk

        // stride-17 padded writes: banks (17L+j)%32 -> 2 lanes/bank (free)
        const int base = 17 * lane;
        #pragma unroll
        for (int j = 0; j < 16; ++j) P[base + j] = E + p[j];

        __builtin_amdgcn_wave_barrier();   // keep write->read order; DS pipe in-order per wave

        const int row = hrow0 + r;         // batch-local row
        if (va && (y1a <= row) && (row < y2a)) acca += P[ra] - P[la];
        if (vb && (y1b <= row) && (row < y2b)) accb += P[rb] - P[lb];

        __builtin_amdgcn_wave_barrier();   // keep next row's writes after these reads
    }

    if (va && acca != 0.0f) atomicAdd(&ws_box[b * NBOX + lane], acca);
    if (vb && accb != 0.0f) atomicAdd(&ws_box[b * NBOX + 64 + lane], accb);
}

// ---------------------------------------------------------------------------
// Kernel 2: loss = sum over boxes of relu(1 - (valid ? box_sum : 0)).
// ---------------------------------------------------------------------------
__global__ void finalize_kernel(const float* __restrict__ ws_box,
                                const int* __restrict__ bboxes,
                                float* __restrict__ out) {
    __shared__ float red[THREADS / 64];
    const int t = threadIdx.x;
    float local = 0.0f;
    for (int idx = t; idx < BATCH * NBOX; idx += THREADS) {
        const int4 q = ((const int4*)bboxes)[idx];
        int x1 = min(max(q.x, 0), WDIM), y1 = min(max(q.y, 0), WDIM);
        int x2 = min(max(q.z, 0), WDIM), y2 = min(max(q.w, 0), WDIM);
        bool valid = (x2 > x1) && (y2 > y1);
        float s = valid ? ws_box[idx] : 0.0f;
        local += fmaxf(1.0f - s, 0.0f);
    }
    #pragma unroll
    for (int off = 32; off > 0; off >>= 1)
        local += __shfl_down(local, off, 64);
    if ((t & 63) == 0) red[t >> 6] = local;
    __syncthreads();
    if (t == 0) {
        float r = 0.0f;
        #pragma unroll
        for (int w = 0; w < THREADS / 64; ++w) r += red[w];
        out[0] = r;
    }
}

// ---------------------------------------------------------------------------
extern "C" void kernel_launch(void* const* d_in, const int* in_sizes, int n_in,
                              void* d_out, int out_size, void* d_ws, size_t ws_size,
                              hipStream_t stream) {
    const float* img    = (const float*)d_in[0];   // (32,1,1024,1024) fp32
    const int*   bboxes = (const int*)d_in[1];     // (32,96,4) int32
    float* out = (float*)d_out;
    float* ws_box = (float*)d_ws;

    zero_ws_kernel<<<(BATCH * NBOX + THREADS - 1) / THREADS, THREADS, 0, stream>>>(ws_box);

    const int nblocks = BATCH * HDIM / (ROWS_PER_WAVE * WAVES_PER_BLOCK);  // 2048
    box_accum_kernel<<<nblocks, THREADS, 0, stream>>>(img, bboxes, ws_box);

    finalize_kernel<<<1, THREADS, 0, stream>>>(ws_box, bboxes, out);
}